// Round 4
// baseline (1318.306 us; speedup 1.0000x reference)
//
#include <hip/hip_runtime.h>
#include <math.h>

// Problem constants (fixed by the reference)
#define BS 4
#define DD 128
#define NN 65536
#define RR 8
#define NSTEPS 6
#define EPSV 1e-6f

#define TPB 256
#define NTILE TPB              // 256 columns per block (1 per thread)
#define NBLK (NN / NTILE)      // 256 blocks per batch
#define NWAVE (TPB / 64)       // 4 waves per block

#define SLOTB (BS * DD * RR)   // per-step bases / n2 slot stride (4096 floats)
#define SLOTC (BS * 64)        // per-step ctc slot stride (256 floats)

// ---------------------------------------------------------------------------
// Cross-lane helpers. DPP quad_perm runs on the VALU pipe (no DS pressure);
// ds_swizzle only for xor4/8/16; shfl_xor(32) for the half-wave hop.
// ---------------------------------------------------------------------------
template <int CTRL>
__device__ __forceinline__ float dpp_add(float x) {
  int y = __builtin_amdgcn_update_dpp(0, __float_as_int(x), CTRL, 0xF, 0xF, true);
  return x + __int_as_float(y);
}
template <int PAT>
__device__ __forceinline__ float swz_add(float x) {
  int y = __builtin_amdgcn_ds_swizzle(__float_as_int(x), PAT);
  return x + __int_as_float(y);
}

// Transpose-reduce 8 per-lane values over the 64-lane wave.
// Returns: every lane holds F[lane&7] = sum over all 64 lanes of p[lane&7].
// Tree order: xor1,2,4,8,16,32 (same associativity as the old shfl version).
__device__ __forceinline__ float tred8(const float p[8], int lane) {
  // level xor1: quad_perm [1,0,3,2] = 0xB1  (VALU/DPP)
  float t0 = dpp_add<0xB1>(p[0]);
  float t1 = dpp_add<0xB1>(p[1]);
  float t2 = dpp_add<0xB1>(p[2]);
  float t3 = dpp_add<0xB1>(p[3]);
  float t4 = dpp_add<0xB1>(p[4]);
  float t5 = dpp_add<0xB1>(p[5]);
  float t6 = dpp_add<0xB1>(p[6]);
  float t7 = dpp_add<0xB1>(p[7]);
  const bool s0 = (lane & 1) != 0;
  float a0 = s0 ? t1 : t0;
  float a1 = s0 ? t3 : t2;
  float a2 = s0 ? t5 : t4;
  float a3 = s0 ? t7 : t6;
  // level xor2: quad_perm [2,3,0,1] = 0x4E  (VALU/DPP)
  float u0 = dpp_add<0x4E>(a0);
  float u1 = dpp_add<0x4E>(a1);
  float u2 = dpp_add<0x4E>(a2);
  float u3 = dpp_add<0x4E>(a3);
  const bool s1 = (lane & 2) != 0;
  float b0 = s1 ? u1 : u0;
  float b1 = s1 ? u3 : u2;
  // level xor4: ds_swizzle
  float w0 = swz_add<0x101F>(b0);
  float w1 = swz_add<0x101F>(b1);
  float v = (lane & 4) ? w1 : w0;
  // cross-group sums: xor8, xor16 via swizzle; xor32 via shfl
  v = swz_add<0x201F>(v);
  v = swz_add<0x401F>(v);
  v += __shfl_xor(v, 32);
  return v;
}

__device__ __forceinline__ void load_row8(const float* __restrict__ p, float v[8]) {
  const float4* s4 = reinterpret_cast<const float4*>(p);
  float4 a = s4[0], b = s4[1];
  v[0] = a.x; v[1] = a.y; v[2] = a.z; v[3] = a.w;
  v[4] = b.x; v[5] = b.y; v[6] = b.z; v[7] = b.w;
}
__device__ __forceinline__ void store_row8(float* __restrict__ p, const float v[8]) {
  float4* s4 = reinterpret_cast<float4*>(p);
  s4[0] = make_float4(v[0], v[1], v[2], v[3]);
  s4[1] = make_float4(v[4], v[5], v[6], v[7]);
}

// ---------------------------------------------------------------------------
// k_init: normalize bases_init (L2 over D) -> bases slot0, compute BtB0,
// zero all per-step accumulator slots. grid = BS, TPB threads.
// ---------------------------------------------------------------------------
__global__ __launch_bounds__(TPB) void k_init(
    const float* __restrict__ bi, float* __restrict__ bases0,
    float* __restrict__ btb0, float* __restrict__ n2acc,
    float* __restrict__ ctcacc) {
  const int b = blockIdx.x;
  const int tid = threadIdx.x;
  __shared__ float nb[DD][RR];
  __shared__ float norms[RR];

  float v[RR];
  if (tid < DD) {
    load_row8(bi + ((size_t)b * DD + tid) * RR, v);
#pragma unroll
    for (int r = 0; r < RR; ++r) nb[tid][r] = v[r] * v[r];
  }
  __syncthreads();
  if (tid < RR) {
    float s = 0.f;
    for (int dd = 0; dd < DD; ++dd) s += nb[dd][tid];
    norms[tid] = fmaxf(sqrtf(s), 1e-12f);
  }
  __syncthreads();
  if (tid < DD) {
#pragma unroll
    for (int r = 0; r < RR; ++r) v[r] = v[r] / norms[r];
    store_row8(bases0 + ((size_t)b * DD + tid) * RR, v);
#pragma unroll
    for (int r = 0; r < RR; ++r) nb[tid][r] = v[r];
  }
  __syncthreads();
  if (tid < 64) {
    const int r = tid >> 3, s2 = tid & 7;
    float acc = 0.f;
    for (int dd = 0; dd < DD; ++dd) acc += nb[dd][r] * nb[dd][s2];
    btb0[b * 64 + tid] = acc;
  }
  for (int s = 0; s < NSTEPS; ++s) {
    for (int i = tid; i < DD * RR; i += TPB)
      n2acc[(size_t)s * SLOTB + b * DD * RR + i] = 0.f;
    if (tid < 64) ctcacc[(size_t)s * SLOTC + b * 64 + tid] = 0.f;
  }
}

// ---------------------------------------------------------------------------
// make_bases: build this step's bases (bl) + BtB (btbl) in LDS.
// FIRST: just load slot0 + btb0. Otherwise compute the multiplicative bases
// update from (bprev, n2prev, ctcprev); block x==0 persists it to bnext.
// ---------------------------------------------------------------------------
template <bool FIRST>
__device__ __forceinline__ void make_bases(
    int b, int tid,
    const float* __restrict__ bprev, const float* __restrict__ btb0,
    const float* __restrict__ n2prev, const float* __restrict__ ctcprev,
    float* __restrict__ bnext, float (&bl)[DD][RR], float* btbl) {
  if (FIRST) {
    reinterpret_cast<float4*>(&bl[0][0])[tid] =
        reinterpret_cast<const float4*>(bprev + (size_t)b * DD * RR)[tid];
    if (tid < 64) btbl[tid] = btb0[b * 64 + tid];
    __syncthreads();
  } else {
    __shared__ float ctcs[64];
    if (tid < 64) ctcs[tid] = ctcprev[b * 64 + tid];
    float row[RR], n2r[RR];
    if (tid < DD) {
      load_row8(bprev + ((size_t)b * DD + tid) * RR, row);
      load_row8(n2prev + ((size_t)b * DD + tid) * RR, n2r);
    }
    __syncthreads();
    float nw[RR];
    if (tid < DD) {
#pragma unroll
      for (int r = 0; r < RR; ++r) {
        float den = EPSV;
#pragma unroll
        for (int s2 = 0; s2 < RR; ++s2) den = fmaf(row[s2], ctcs[s2 * 8 + r], den);
        nw[r] = row[r] * n2r[r] / den;
      }
#pragma unroll
      for (int r = 0; r < RR; ++r) bl[tid][r] = nw[r];
      if (bnext != nullptr && blockIdx.x == 0)
        store_row8(bnext + ((size_t)b * DD + tid) * RR, nw);
    }
    __syncthreads();
    if (tid < 64) {
      const int r = tid >> 3, s2 = tid & 7;
      float acc = 0.f;
      for (int dd = 0; dd < DD; ++dd) acc += bl[dd][r] * bl[dd][s2];
      btbl[tid] = acc;
    }
    __syncthreads();
  }
}

// ---------------------------------------------------------------------------
// k_step<FIRST>: single x read into registers, then:
//   s = x^T bl;  coef_new = (FIRST ? softmax(s) : coef) * s / (coef@BtB+eps)
//   n2cur += x (regs) * coef_new;  ctccur += coef_new^T coef_new
// grid = (NBLK, BS), TPB threads.
// ---------------------------------------------------------------------------
template <bool FIRST>
__global__ __launch_bounds__(TPB) void k_step(
    const float* __restrict__ xf, float* __restrict__ coef,
    const float* __restrict__ bprev, const float* __restrict__ btb0,
    const float* __restrict__ n2prev, const float* __restrict__ ctcprev,
    float* __restrict__ bnext,
    float* __restrict__ n2cur, float* __restrict__ ctccur) {
  const int b = blockIdx.y;
  const int tid = threadIdx.x;
  const int lane = tid & 63;
  const int wv = tid >> 6;
  const size_t n0 = (size_t)blockIdx.x * NTILE + tid;
  const float* __restrict__ xb = xf + (size_t)b * DD * NN + n0;

  __shared__ float bl[DD][RR];          // 4 KB
  __shared__ float btbl[64];            // 256 B
  __shared__ float nlds[NWAVE][DD][RR]; // 16 KB
  __shared__ float ctcl[NWAVE][64];     // 1 KB

  make_bases<FIRST>(b, tid, bprev, btb0, n2prev, ctcprev, bnext, bl, btbl);

  // ---- single memory pass: whole column into registers (max MLP)
  float xr[DD];
#pragma unroll
  for (int d = 0; d < DD; ++d) xr[d] = xb[(size_t)d * NN];

  // ---- s = x^T bl (pure VALU + broadcast LDS reads)
  float s_[RR] = {0.f, 0.f, 0.f, 0.f, 0.f, 0.f, 0.f, 0.f};
#pragma unroll
  for (int d = 0; d < DD; ++d) {
    const float4 b03 = *reinterpret_cast<const float4*>(&bl[d][0]);
    const float4 b47 = *reinterpret_cast<const float4*>(&bl[d][4]);
    s_[0] = fmaf(xr[d], b03.x, s_[0]);
    s_[1] = fmaf(xr[d], b03.y, s_[1]);
    s_[2] = fmaf(xr[d], b03.z, s_[2]);
    s_[3] = fmaf(xr[d], b03.w, s_[3]);
    s_[4] = fmaf(xr[d], b47.x, s_[4]);
    s_[5] = fmaf(xr[d], b47.y, s_[5]);
    s_[6] = fmaf(xr[d], b47.z, s_[6]);
    s_[7] = fmaf(xr[d], b47.w, s_[7]);
  }

  // ---- coef update
  float* cp = coef + ((size_t)b * NN + n0) * RR;
  float c[RR];
  if (FIRST) {
    float m = s_[0];
#pragma unroll
    for (int r = 1; r < RR; ++r) m = fmaxf(m, s_[r]);
    float sum = 0.f;
#pragma unroll
    for (int r = 0; r < RR; ++r) {
      float e = __expf(s_[r] - m);
      c[r] = e;
      sum += e;
    }
#pragma unroll
    for (int r = 0; r < RR; ++r) c[r] = c[r] / sum;
  } else {
    load_row8(cp, c);
  }
  {
    float cn[RR];
#pragma unroll
    for (int r = 0; r < RR; ++r) {
      float dv = EPSV;
#pragma unroll
      for (int t2 = 0; t2 < RR; ++t2) dv = fmaf(c[t2], btbl[t2 * 8 + r], dv);
      cn[r] = c[r] * s_[r] / dv;
    }
#pragma unroll
    for (int r = 0; r < RR; ++r) c[r] = cn[r];
  }
  store_row8(cp, c);

  // ---- n2 contribution from registers (no second memory pass)
#pragma unroll
  for (int d = 0; d < DD; ++d) {
    float p[RR];
#pragma unroll
    for (int r = 0; r < RR; ++r) p[r] = xr[d] * c[r];
    float v = tred8(p, lane);
    if (lane < RR) nlds[wv][d][lane] = v;
  }
  // ---- CtC
#pragma unroll
  for (int r = 0; r < RR; ++r) {
    float p2[RR];
#pragma unroll
    for (int s2 = 0; s2 < RR; ++s2) p2[s2] = c[r] * c[s2];
    float v = tred8(p2, lane);
    if (lane < RR) ctcl[wv][r * 8 + lane] = v;
  }
  __syncthreads();

  const float* nf = &nlds[0][0][0];
  for (int i = tid; i < DD * RR; i += TPB) {
    float acc = nf[i] + nf[DD * RR + i] + nf[2 * DD * RR + i] + nf[3 * DD * RR + i];
    atomicAdd(&n2cur[b * DD * RR + i], acc);
  }
  if (tid < 64) {
    float acc = ctcl[0][tid] + ctcl[1][tid] + ctcl[2][tid] + ctcl[3][tid];
    atomicAdd(&ctccur[b * 64 + tid], acc);
  }
}

// ---------------------------------------------------------------------------
// k_final: bases_6 prologue + last coef update (compute_coef) fused with
// reconstruction out = bl @ coef^T. grid = (NBLK, BS), TPB threads.
// ---------------------------------------------------------------------------
__global__ __launch_bounds__(TPB) void k_final(
    const float* __restrict__ xf, const float* __restrict__ coef,
    const float* __restrict__ bprev, const float* __restrict__ n2prev,
    const float* __restrict__ ctcprev, float* __restrict__ out) {
  const int b = blockIdx.y;
  const int tid = threadIdx.x;
  const size_t n0 = (size_t)blockIdx.x * NTILE + tid;
  const float* __restrict__ xb = xf + (size_t)b * DD * NN + n0;

  __shared__ float bl[DD][RR];
  __shared__ float btbl[64];

  make_bases<false>(b, tid, bprev, nullptr, n2prev, ctcprev, nullptr, bl, btbl);

  float s_[RR] = {0.f, 0.f, 0.f, 0.f, 0.f, 0.f, 0.f, 0.f};
#pragma unroll 16
  for (int d = 0; d < DD; ++d) {
    const float xv = xb[(size_t)d * NN];
    const float4 b03 = *reinterpret_cast<const float4*>(&bl[d][0]);
    const float4 b47 = *reinterpret_cast<const float4*>(&bl[d][4]);
    s_[0] = fmaf(xv, b03.x, s_[0]);
    s_[1] = fmaf(xv, b03.y, s_[1]);
    s_[2] = fmaf(xv, b03.z, s_[2]);
    s_[3] = fmaf(xv, b03.w, s_[3]);
    s_[4] = fmaf(xv, b47.x, s_[4]);
    s_[5] = fmaf(xv, b47.y, s_[5]);
    s_[6] = fmaf(xv, b47.z, s_[6]);
    s_[7] = fmaf(xv, b47.w, s_[7]);
  }

  float c[RR];
  load_row8(coef + ((size_t)b * NN + n0) * RR, c);
  {
    float cn[RR];
#pragma unroll
    for (int r = 0; r < RR; ++r) {
      float dv = EPSV;
#pragma unroll
      for (int t2 = 0; t2 < RR; ++t2) dv = fmaf(c[t2], btbl[t2 * 8 + r], dv);
      cn[r] = c[r] * s_[r] / dv;
    }
#pragma unroll
    for (int r = 0; r < RR; ++r) c[r] = cn[r];
  }

  float* ob = out + (size_t)b * DD * NN + n0;
#pragma unroll 8
  for (int d = 0; d < DD; ++d) {
    const float4 b03 = *reinterpret_cast<const float4*>(&bl[d][0]);
    const float4 b47 = *reinterpret_cast<const float4*>(&bl[d][4]);
    float o = b03.x * c[0];
    o = fmaf(b03.y, c[1], o);
    o = fmaf(b03.z, c[2], o);
    o = fmaf(b03.w, c[3], o);
    o = fmaf(b47.x, c[4], o);
    o = fmaf(b47.y, c[5], o);
    o = fmaf(b47.z, c[6], o);
    o = fmaf(b47.w, c[7], o);
    ob[(size_t)d * NN] = o;
  }
}

// ---------------------------------------------------------------------------
extern "C" void kernel_launch(void* const* d_in, const int* in_sizes, int n_in,
                              void* d_out, int out_size, void* d_ws, size_t ws_size,
                              hipStream_t stream) {
  const float* x = (const float*)d_in[0];   // [BS, DD, NN] fp32
  const float* bi = (const float*)d_in[1];  // [BS, DD, RR] fp32
  float* out = (float*)d_out;               // [BS, DD, NN] fp32

  // workspace (floats): coef | bases_store[6] | btb0 | n2acc[6] | ctcacc[6]
  float* coef = (float*)d_ws;                          // BS*NN*RR
  float* bases_store = coef + (size_t)BS * NN * RR;    // 6 * SLOTB
  float* btb0 = bases_store + (size_t)6 * SLOTB;       // BS*64
  float* n2acc = btb0 + (size_t)BS * 64;               // 6 * SLOTB
  float* ctcacc = n2acc + (size_t)6 * SLOTB;           // 6 * SLOTC

  dim3 gbig(NBLK, BS);

  k_init<<<dim3(BS), TPB, 0, stream>>>(bi, bases_store, btb0, n2acc, ctcacc);

  k_step<true><<<gbig, TPB, 0, stream>>>(x, coef, bases_store, btb0, nullptr,
                                         nullptr, nullptr, n2acc, ctcacc);
  for (int s = 1; s < NSTEPS; ++s) {
    k_step<false><<<gbig, TPB, 0, stream>>>(
        x, coef, bases_store + (size_t)(s - 1) * SLOTB, nullptr,
        n2acc + (size_t)(s - 1) * SLOTB, ctcacc + (size_t)(s - 1) * SLOTC,
        bases_store + (size_t)s * SLOTB, n2acc + (size_t)s * SLOTB,
        ctcacc + (size_t)s * SLOTC);
  }

  k_final<<<gbig, TPB, 0, stream>>>(
      x, coef, bases_store + (size_t)5 * SLOTB, n2acc + (size_t)5 * SLOTB,
      ctcacc + (size_t)5 * SLOTC, out);
}

// Round 7
// 586.393 us; speedup vs baseline: 2.2482x; 2.2482x over previous
//
#include <hip/hip_runtime.h>
#include <math.h>

// Problem constants (fixed by the reference)
#define BS 4
#define DD 128
#define NN 65536
#define RR 8
#define NSTEPS 6
#define EPSV 1e-6f

#define TPB 256
#define NPT 2
#define NTILE (TPB * NPT)      // 512 columns per block
#define NBLK (NN / NTILE)      // 128 blocks per batch -> 512 blocks total
#define NWAVE (TPB / 64)       // 4 waves per block
#define GSTEP 16               // staged-load depth (16 float2 in flight)

#define SLOTB (BS * DD * RR)   // per-step bases / n2 slot stride (4096 floats)
#define SLOTC (BS * 64)        // per-step ctc slot stride (256 floats)

// ---------------------------------------------------------------------------
// Cross-lane helpers. DPP quad_perm runs on the VALU pipe; ds_swizzle only
// for xor4/8/16; shfl_xor(32) for the half-wave hop. (Validated in round 4.)
// ---------------------------------------------------------------------------
template <int CTRL>
__device__ __forceinline__ float dpp_add(float x) {
  int y = __builtin_amdgcn_update_dpp(0, __float_as_int(x), CTRL, 0xF, 0xF, true);
  return x + __int_as_float(y);
}
template <int PAT>
__device__ __forceinline__ float swz_add(float x) {
  int y = __builtin_amdgcn_ds_swizzle(__float_as_int(x), PAT);
  return x + __int_as_float(y);
}

// Transpose-reduce 8 per-lane values over the 64-lane wave.
// Every lane returns F[lane&7] = sum over all 64 lanes of p[lane&7].
__device__ __forceinline__ float tred8(const float p[8], int lane) {
  float t0 = dpp_add<0xB1>(p[0]);   // xor1 via quad_perm [1,0,3,2]
  float t1 = dpp_add<0xB1>(p[1]);
  float t2 = dpp_add<0xB1>(p[2]);
  float t3 = dpp_add<0xB1>(p[3]);
  float t4 = dpp_add<0xB1>(p[4]);
  float t5 = dpp_add<0xB1>(p[5]);
  float t6 = dpp_add<0xB1>(p[6]);
  float t7 = dpp_add<0xB1>(p[7]);
  const bool s0 = (lane & 1) != 0;
  float a0 = s0 ? t1 : t0;
  float a1 = s0 ? t3 : t2;
  float a2 = s0 ? t5 : t4;
  float a3 = s0 ? t7 : t6;
  float u0 = dpp_add<0x4E>(a0);     // xor2 via quad_perm [2,3,0,1]
  float u1 = dpp_add<0x4E>(a1);
  float u2 = dpp_add<0x4E>(a2);
  float u3 = dpp_add<0x4E>(a3);
  const bool s1 = (lane & 2) != 0;
  float b0 = s1 ? u1 : u0;
  float b1 = s1 ? u3 : u2;
  float w0 = swz_add<0x101F>(b0);   // xor4
  float w1 = swz_add<0x101F>(b1);
  float v = (lane & 4) ? w1 : w0;
  v = swz_add<0x201F>(v);           // xor8
  v = swz_add<0x401F>(v);           // xor16
  v += __shfl_xor(v, 32);           // xor32
  return v;
}

__device__ __forceinline__ void load_row8(const float* __restrict__ p, float v[8]) {
  const float4* s4 = reinterpret_cast<const float4*>(p);
  float4 a = s4[0], b = s4[1];
  v[0] = a.x; v[1] = a.y; v[2] = a.z; v[3] = a.w;
  v[4] = b.x; v[5] = b.y; v[6] = b.z; v[7] = b.w;
}
__device__ __forceinline__ void store_row8(float* __restrict__ p, const float v[8]) {
  float4* s4 = reinterpret_cast<float4*>(p);
  s4[0] = make_float4(v[0], v[1], v[2], v[3]);
  s4[1] = make_float4(v[4], v[5], v[6], v[7]);
}

// ---------------------------------------------------------------------------
// k_init: normalize bases_init (L2 over D) -> bases slot0, compute BtB0,
// zero all per-step accumulator slots. grid = BS, TPB threads.
// ---------------------------------------------------------------------------
__global__ __launch_bounds__(TPB) void k_init(
    const float* __restrict__ bi, float* __restrict__ bases0,
    float* __restrict__ btb0, float* __restrict__ n2acc,
    float* __restrict__ ctcacc) {
  const int b = blockIdx.x;
  const int tid = threadIdx.x;
  __shared__ float nb[DD][RR];
  __shared__ float norms[RR];

  float v[RR];
  if (tid < DD) {
    load_row8(bi + ((size_t)b * DD + tid) * RR, v);
#pragma unroll
    for (int r = 0; r < RR; ++r) nb[tid][r] = v[r] * v[r];
  }
  __syncthreads();
  if (tid < RR) {
    float s = 0.f;
    for (int dd = 0; dd < DD; ++dd) s += nb[dd][tid];
    norms[tid] = fmaxf(sqrtf(s), 1e-12f);
  }
  __syncthreads();
  if (tid < DD) {
#pragma unroll
    for (int r = 0; r < RR; ++r) v[r] = v[r] / norms[r];
    store_row8(bases0 + ((size_t)b * DD + tid) * RR, v);
#pragma unroll
    for (int r = 0; r < RR; ++r) nb[tid][r] = v[r];
  }
  __syncthreads();
  if (tid < 64) {
    const int r = tid >> 3, s2 = tid & 7;
    float acc = 0.f;
    for (int dd = 0; dd < DD; ++dd) acc += nb[dd][r] * nb[dd][s2];
    btb0[b * 64 + tid] = acc;
  }
  for (int s = 0; s < NSTEPS; ++s) {
    for (int i = tid; i < DD * RR; i += TPB)
      n2acc[(size_t)s * SLOTB + b * DD * RR + i] = 0.f;
    if (tid < 64) ctcacc[(size_t)s * SLOTC + b * 64 + tid] = 0.f;
  }
}

// ---------------------------------------------------------------------------
// make_bases: build this step's bases (bl) + BtB (btbl) in LDS.
// FIRST: load slot0 + btb0. Otherwise compute the multiplicative bases
// update from (bprev, n2prev, ctcprev); block x==0 persists it to bnext.
// ---------------------------------------------------------------------------
template <bool FIRST>
__device__ __forceinline__ void make_bases(
    int b, int tid,
    const float* __restrict__ bprev, const float* __restrict__ btb0,
    const float* __restrict__ n2prev, const float* __restrict__ ctcprev,
    float* __restrict__ bnext, float (&bl)[DD][RR], float* btbl) {
  if (FIRST) {
    reinterpret_cast<float4*>(&bl[0][0])[tid] =
        reinterpret_cast<const float4*>(bprev + (size_t)b * DD * RR)[tid];
    if (tid < 64) btbl[tid] = btb0[b * 64 + tid];
    __syncthreads();
  } else {
    __shared__ float ctcs[64];
    if (tid < 64) ctcs[tid] = ctcprev[b * 64 + tid];
    float row[RR], n2r[RR];
    if (tid < DD) {
      load_row8(bprev + ((size_t)b * DD + tid) * RR, row);
      load_row8(n2prev + ((size_t)b * DD + tid) * RR, n2r);
    }
    __syncthreads();
    float nw[RR];
    if (tid < DD) {
#pragma unroll
      for (int r = 0; r < RR; ++r) {
        float den = EPSV;
#pragma unroll
        for (int s2 = 0; s2 < RR; ++s2) den = fmaf(row[s2], ctcs[s2 * 8 + r], den);
        nw[r] = row[r] * n2r[r] / den;
      }
#pragma unroll
      for (int r = 0; r < RR; ++r) bl[tid][r] = nw[r];
      if (bnext != nullptr && blockIdx.x == 0)
        store_row8(bnext + ((size_t)b * DD + tid) * RR, nw);
    }
    __syncthreads();
    if (tid < 64) {
      const int r = tid >> 3, s2 = tid & 7;
      float acc = 0.f;
      for (int dd = 0; dd < DD; ++dd) acc += bl[dd][r] * bl[dd][s2];
      btbl[tid] = acc;
    }
    __syncthreads();
  }
}

// ---------------------------------------------------------------------------
// k_step<FIRST>: per 512-column tile, two passes over x with 16-deep staged
// loads (explicit MLP):
//   pass1: s = x^T bl;  coef_new = (FIRST ? softmax(s) : coef)*s/(coef@BtB+e)
//   pass2: n2cur += x * coef_new (re-read, L2-hot); ctccur += c^T c
// grid = (NBLK, BS), TPB threads.
// ---------------------------------------------------------------------------
template <bool FIRST>
__global__ __launch_bounds__(TPB) void k_step(
    const float* __restrict__ xf, float* __restrict__ coef,
    const float* __restrict__ bprev, const float* __restrict__ btb0,
    const float* __restrict__ n2prev, const float* __restrict__ ctcprev,
    float* __restrict__ bnext,
    float* __restrict__ n2cur, float* __restrict__ ctccur) {
  const int b = blockIdx.y;
  const int tid = threadIdx.x;
  const int lane = tid & 63;
  const int wv = tid >> 6;
  const size_t n0 = (size_t)blockIdx.x * NTILE + (size_t)tid * NPT;
  const float* __restrict__ xb = xf + (size_t)b * DD * NN + n0;

  __shared__ float bl[DD][RR];          // 4 KB
  __shared__ float btbl[64];            // 256 B
  __shared__ float nlds[NWAVE][DD][RR]; // 16 KB
  __shared__ float ctcl[NWAVE][64];     // 1 KB

  make_bases<FIRST>(b, tid, bprev, btb0, n2prev, ctcprev, bnext, bl, btbl);

  // ---- pass 1: s = x^T bl, 16 staged loads per group
  float s0_[RR] = {0.f, 0.f, 0.f, 0.f, 0.f, 0.f, 0.f, 0.f};
  float s1_[RR] = {0.f, 0.f, 0.f, 0.f, 0.f, 0.f, 0.f, 0.f};
#pragma unroll 1
  for (int g = 0; g < DD / GSTEP; ++g) {
    float2 buf[GSTEP];
#pragma unroll
    for (int k = 0; k < GSTEP; ++k)
      buf[k] = *reinterpret_cast<const float2*>(xb + (size_t)(g * GSTEP + k) * NN);
#pragma unroll
    for (int k = 0; k < GSTEP; ++k) {
      const int d = g * GSTEP + k;
      const float4 b03 = *reinterpret_cast<const float4*>(&bl[d][0]);
      const float4 b47 = *reinterpret_cast<const float4*>(&bl[d][4]);
      s0_[0] = fmaf(buf[k].x, b03.x, s0_[0]);
      s0_[1] = fmaf(buf[k].x, b03.y, s0_[1]);
      s0_[2] = fmaf(buf[k].x, b03.z, s0_[2]);
      s0_[3] = fmaf(buf[k].x, b03.w, s0_[3]);
      s0_[4] = fmaf(buf[k].x, b47.x, s0_[4]);
      s0_[5] = fmaf(buf[k].x, b47.y, s0_[5]);
      s0_[6] = fmaf(buf[k].x, b47.z, s0_[6]);
      s0_[7] = fmaf(buf[k].x, b47.w, s0_[7]);
      s1_[0] = fmaf(buf[k].y, b03.x, s1_[0]);
      s1_[1] = fmaf(buf[k].y, b03.y, s1_[1]);
      s1_[2] = fmaf(buf[k].y, b03.z, s1_[2]);
      s1_[3] = fmaf(buf[k].y, b03.w, s1_[3]);
      s1_[4] = fmaf(buf[k].y, b47.x, s1_[4]);
      s1_[5] = fmaf(buf[k].y, b47.y, s1_[5]);
      s1_[6] = fmaf(buf[k].y, b47.z, s1_[6]);
      s1_[7] = fmaf(buf[k].y, b47.w, s1_[7]);
    }
  }

  // ---- coef update (both columns)
  float* cp = coef + ((size_t)b * NN + n0) * RR;
  float c0[RR], c1[RR];
  if (FIRST) {
    float m0 = s0_[0], m1 = s1_[0];
#pragma unroll
    for (int r = 1; r < RR; ++r) { m0 = fmaxf(m0, s0_[r]); m1 = fmaxf(m1, s1_[r]); }
    float sum0 = 0.f, sum1 = 0.f;
#pragma unroll
    for (int r = 0; r < RR; ++r) {
      float e0 = __expf(s0_[r] - m0), e1 = __expf(s1_[r] - m1);
      c0[r] = e0; c1[r] = e1; sum0 += e0; sum1 += e1;
    }
#pragma unroll
    for (int r = 0; r < RR; ++r) { c0[r] /= sum0; c1[r] /= sum1; }
  } else {
    load_row8(cp, c0);
    load_row8(cp + RR, c1);
  }
  {
    float cn0[RR], cn1[RR];
#pragma unroll
    for (int r = 0; r < RR; ++r) {
      float d0 = EPSV, d1 = EPSV;
#pragma unroll
      for (int t2 = 0; t2 < RR; ++t2) {
        const float bb = btbl[t2 * 8 + r];
        d0 = fmaf(c0[t2], bb, d0);
        d1 = fmaf(c1[t2], bb, d1);
      }
      cn0[r] = c0[r] * s0_[r] / d0;
      cn1[r] = c1[r] * s1_[r] / d1;
    }
#pragma unroll
    for (int r = 0; r < RR; ++r) { c0[r] = cn0[r]; c1[r] = cn1[r]; }
  }
  store_row8(cp, c0);
  store_row8(cp + RR, c1);

  // ---- pass 2: n2[d][r] += x[d][n]*c[n][r], staged re-read (L2-hot)
#pragma unroll 1
  for (int g = 0; g < DD / GSTEP; ++g) {
    float2 buf[GSTEP];
#pragma unroll
    for (int k = 0; k < GSTEP; ++k)
      buf[k] = *reinterpret_cast<const float2*>(xb + (size_t)(g * GSTEP + k) * NN);
#pragma unroll
    for (int k = 0; k < GSTEP; ++k) {
      const int d = g * GSTEP + k;
      float p[RR];
#pragma unroll
      for (int r = 0; r < RR; ++r) p[r] = fmaf(buf[k].x, c0[r], buf[k].y * c1[r]);
      float v = tred8(p, lane);
      if (lane < RR) nlds[wv][d][lane] = v;
    }
  }
  // ---- CtC
#pragma unroll
  for (int r = 0; r < RR; ++r) {
    float p2[RR];
#pragma unroll
    for (int s2 = 0; s2 < RR; ++s2) p2[s2] = c0[r] * c0[s2] + c1[r] * c1[s2];
    float v = tred8(p2, lane);
    if (lane < RR) ctcl[wv][r * 8 + lane] = v;
  }
  __syncthreads();

  const float* nf = &nlds[0][0][0];
  for (int i = tid; i < DD * RR; i += TPB) {
    float acc = nf[i] + nf[DD * RR + i] + nf[2 * DD * RR + i] + nf[3 * DD * RR + i];
    atomicAdd(&n2cur[b * DD * RR + i], acc);
  }
  if (tid < 64) {
    float acc = ctcl[0][tid] + ctcl[1][tid] + ctcl[2][tid] + ctcl[3][tid];
    atomicAdd(&ctccur[b * 64 + tid], acc);
  }
}

// ---------------------------------------------------------------------------
// k_final: bases_6 prologue + last coef update (compute_coef) fused with
// reconstruction out = bl @ coef^T. grid = (NBLK, BS), TPB threads.
// ---------------------------------------------------------------------------
__global__ __launch_bounds__(TPB) void k_final(
    const float* __restrict__ xf, const float* __restrict__ coef,
    const float* __restrict__ bprev, const float* __restrict__ n2prev,
    const float* __restrict__ ctcprev, float* __restrict__ out) {
  const int b = blockIdx.y;
  const int tid = threadIdx.x;
  const size_t n0 = (size_t)blockIdx.x * NTILE + (size_t)tid * NPT;
  const float* __restrict__ xb = xf + (size_t)b * DD * NN + n0;

  __shared__ float bl[DD][RR];
  __shared__ float btbl[64];

  make_bases<false>(b, tid, bprev, nullptr, n2prev, ctcprev, nullptr, bl, btbl);

  float s0_[RR] = {0.f, 0.f, 0.f, 0.f, 0.f, 0.f, 0.f, 0.f};
  float s1_[RR] = {0.f, 0.f, 0.f, 0.f, 0.f, 0.f, 0.f, 0.f};
#pragma unroll 1
  for (int g = 0; g < DD / GSTEP; ++g) {
    float2 buf[GSTEP];
#pragma unroll
    for (int k = 0; k < GSTEP; ++k)
      buf[k] = *reinterpret_cast<const float2*>(xb + (size_t)(g * GSTEP + k) * NN);
#pragma unroll
    for (int k = 0; k < GSTEP; ++k) {
      const int d = g * GSTEP + k;
      const float4 b03 = *reinterpret_cast<const float4*>(&bl[d][0]);
      const float4 b47 = *reinterpret_cast<const float4*>(&bl[d][4]);
      s0_[0] = fmaf(buf[k].x, b03.x, s0_[0]);
      s0_[1] = fmaf(buf[k].x, b03.y, s0_[1]);
      s0_[2] = fmaf(buf[k].x, b03.z, s0_[2]);
      s0_[3] = fmaf(buf[k].x, b03.w, s0_[3]);
      s0_[4] = fmaf(buf[k].x, b47.x, s0_[4]);
      s0_[5] = fmaf(buf[k].x, b47.y, s0_[5]);
      s0_[6] = fmaf(buf[k].x, b47.z, s0_[6]);
      s0_[7] = fmaf(buf[k].x, b47.w, s0_[7]);
      s1_[0] = fmaf(buf[k].y, b03.x, s1_[0]);
      s1_[1] = fmaf(buf[k].y, b03.y, s1_[1]);
      s1_[2] = fmaf(buf[k].y, b03.z, s1_[2]);
      s1_[3] = fmaf(buf[k].y, b03.w, s1_[3]);
      s1_[4] = fmaf(buf[k].y, b47.x, s1_[4]);
      s1_[5] = fmaf(buf[k].y, b47.y, s1_[5]);
      s1_[6] = fmaf(buf[k].y, b47.z, s1_[6]);
      s1_[7] = fmaf(buf[k].y, b47.w, s1_[7]);
    }
  }

  float c0[RR], c1[RR];
  const float* cp = coef + ((size_t)b * NN + n0) * RR;
  load_row8(cp, c0);
  load_row8(cp + RR, c1);
  {
    float cn0[RR], cn1[RR];
#pragma unroll
    for (int r = 0; r < RR; ++r) {
      float d0 = EPSV, d1 = EPSV;
#pragma unroll
      for (int t2 = 0; t2 < RR; ++t2) {
        const float bb = btbl[t2 * 8 + r];
        d0 = fmaf(c0[t2], bb, d0);
        d1 = fmaf(c1[t2], bb, d1);
      }
      cn0[r] = c0[r] * s0_[r] / d0;
      cn1[r] = c1[r] * s1_[r] / d1;
    }
#pragma unroll
    for (int r = 0; r < RR; ++r) { c0[r] = cn0[r]; c1[r] = cn1[r]; }
  }

  float* ob = out + (size_t)b * DD * NN + n0;
#pragma unroll 4
  for (int d = 0; d < DD; ++d) {
    const float4 b03 = *reinterpret_cast<const float4*>(&bl[d][0]);
    const float4 b47 = *reinterpret_cast<const float4*>(&bl[d][4]);
    float ox = b03.x * c0[0], oy = b03.x * c1[0];
    ox = fmaf(b03.y, c0[1], ox); oy = fmaf(b03.y, c1[1], oy);
    ox = fmaf(b03.z, c0[2], ox); oy = fmaf(b03.z, c1[2], oy);
    ox = fmaf(b03.w, c0[3], ox); oy = fmaf(b03.w, c1[3], oy);
    ox = fmaf(b47.x, c0[4], ox); oy = fmaf(b47.x, c1[4], oy);
    ox = fmaf(b47.y, c0[5], ox); oy = fmaf(b47.y, c1[5], oy);
    ox = fmaf(b47.z, c0[6], ox); oy = fmaf(b47.z, c1[6], oy);
    ox = fmaf(b47.w, c0[7], ox); oy = fmaf(b47.w, c1[7], oy);
    *reinterpret_cast<float2*>(ob + (size_t)d * NN) = make_float2(ox, oy);
  }
}

// ---------------------------------------------------------------------------
extern "C" void kernel_launch(void* const* d_in, const int* in_sizes, int n_in,
                              void* d_out, int out_size, void* d_ws, size_t ws_size,
                              hipStream_t stream) {
  const float* x = (const float*)d_in[0];   // [BS, DD, NN] fp32
  const float* bi = (const float*)d_in[1];  // [BS, DD, RR] fp32
  float* out = (float*)d_out;               // [BS, DD, NN] fp32

  // workspace (floats): coef | bases_store[6] | btb0 | n2acc[6] | ctcacc[6]
  float* coef = (float*)d_ws;                          // BS*NN*RR
  float* bases_store = coef + (size_t)BS * NN * RR;    // 6 * SLOTB
  float* btb0 = bases_store + (size_t)6 * SLOTB;       // BS*64
  float* n2acc = btb0 + (size_t)BS * 64;               // 6 * SLOTB
  float* ctcacc = n2acc + (size_t)6 * SLOTB;           // 6 * SLOTC

  dim3 gbig(NBLK, BS);

  k_init<<<dim3(BS), TPB, 0, stream>>>(bi, bases_store, btb0, n2acc, ctcacc);

  k_step<true><<<gbig, TPB, 0, stream>>>(x, coef, bases_store, btb0, nullptr,
                                         nullptr, nullptr, n2acc, ctcacc);
  for (int s = 1; s < NSTEPS; ++s) {
    k_step<false><<<gbig, TPB, 0, stream>>>(
        x, coef, bases_store + (size_t)(s - 1) * SLOTB, nullptr,
        n2acc + (size_t)(s - 1) * SLOTB, ctcacc + (size_t)(s - 1) * SLOTC,
        bases_store + (size_t)s * SLOTB, n2acc + (size_t)s * SLOTB,
        ctcacc + (size_t)s * SLOTC);
  }

  k_final<<<gbig, TPB, 0, stream>>>(
      x, coef, bases_store + (size_t)5 * SLOTB, n2acc + (size_t)5 * SLOTB,
      ctcacc + (size_t)5 * SLOTC, out);
}

// Round 8
// 575.358 us; speedup vs baseline: 2.2913x; 1.0192x over previous
//
#include <hip/hip_runtime.h>
#include <math.h>

// Problem constants (fixed by the reference)
#define BS 4
#define DD 128
#define NN 65536
#define RR 8
#define NSTEPS 6
#define EPSV 1e-6f

#define TPB 256
#define NPT 2
#define NTILE (TPB * NPT)      // 512 columns per block
#define NBLK (NN / NTILE)      // 128 blocks per batch -> 512 blocks total
#define NWAVE (TPB / 64)       // 4 waves per block
#define GSTEP 16               // staged-load depth (16 float2 in flight)

#define SLOTB (BS * DD * RR)   // per-step bases / n2 slot stride (4096 floats)
#define SLOTC (BS * 64)        // per-step ctc slot stride (256 floats)

// ---------------------------------------------------------------------------
// Cross-lane helpers. DPP quad_perm runs on the VALU pipe; ds_swizzle only
// for xor4/8/16; shfl_xor(32) for the half-wave hop. (Validated round 4/7.)
// ---------------------------------------------------------------------------
template <int CTRL>
__device__ __forceinline__ float dpp_add(float x) {
  int y = __builtin_amdgcn_update_dpp(0, __float_as_int(x), CTRL, 0xF, 0xF, true);
  return x + __int_as_float(y);
}
template <int PAT>
__device__ __forceinline__ float swz_add(float x) {
  int y = __builtin_amdgcn_ds_swizzle(__float_as_int(x), PAT);
  return x + __int_as_float(y);
}

// Transpose-reduce 8 per-lane values over the 64-lane wave.
// Every lane returns F[lane&7] = sum over all 64 lanes of p[lane&7].
__device__ __forceinline__ float tred8(const float p[8], int lane) {
  float t0 = dpp_add<0xB1>(p[0]);   // xor1 via quad_perm [1,0,3,2]
  float t1 = dpp_add<0xB1>(p[1]);
  float t2 = dpp_add<0xB1>(p[2]);
  float t3 = dpp_add<0xB1>(p[3]);
  float t4 = dpp_add<0xB1>(p[4]);
  float t5 = dpp_add<0xB1>(p[5]);
  float t6 = dpp_add<0xB1>(p[6]);
  float t7 = dpp_add<0xB1>(p[7]);
  const bool s0 = (lane & 1) != 0;
  float a0 = s0 ? t1 : t0;
  float a1 = s0 ? t3 : t2;
  float a2 = s0 ? t5 : t4;
  float a3 = s0 ? t7 : t6;
  float u0 = dpp_add<0x4E>(a0);     // xor2 via quad_perm [2,3,0,1]
  float u1 = dpp_add<0x4E>(a1);
  float u2 = dpp_add<0x4E>(a2);
  float u3 = dpp_add<0x4E>(a3);
  const bool s1 = (lane & 2) != 0;
  float b0 = s1 ? u1 : u0;
  float b1 = s1 ? u3 : u2;
  float w0 = swz_add<0x101F>(b0);   // xor4
  float w1 = swz_add<0x101F>(b1);
  float v = (lane & 4) ? w1 : w0;
  v = swz_add<0x201F>(v);           // xor8
  v = swz_add<0x401F>(v);           // xor16
  v += __shfl_xor(v, 32);           // xor32
  return v;
}

__device__ __forceinline__ void load_row8(const float* __restrict__ p, float v[8]) {
  const float4* s4 = reinterpret_cast<const float4*>(p);
  float4 a = s4[0], b = s4[1];
  v[0] = a.x; v[1] = a.y; v[2] = a.z; v[3] = a.w;
  v[4] = b.x; v[5] = b.y; v[6] = b.z; v[7] = b.w;
}
__device__ __forceinline__ void store_row8(float* __restrict__ p, const float v[8]) {
  float4* s4 = reinterpret_cast<float4*>(p);
  s4[0] = make_float4(v[0], v[1], v[2], v[3]);
  s4[1] = make_float4(v[4], v[5], v[6], v[7]);
}

// ---------------------------------------------------------------------------
// k_init: normalize bases_init (L2 over D) -> bases slot0, compute BtB0,
// zero all per-step accumulator slots. grid = BS, TPB threads.
// ---------------------------------------------------------------------------
__global__ __launch_bounds__(TPB) void k_init(
    const float* __restrict__ bi, float* __restrict__ bases0,
    float* __restrict__ btb0, float* __restrict__ n2acc,
    float* __restrict__ ctcacc) {
  const int b = blockIdx.x;
  const int tid = threadIdx.x;
  __shared__ float nb[DD][RR];
  __shared__ float norms[RR];

  float v[RR];
  if (tid < DD) {
    load_row8(bi + ((size_t)b * DD + tid) * RR, v);
#pragma unroll
    for (int r = 0; r < RR; ++r) nb[tid][r] = v[r] * v[r];
  }
  __syncthreads();
  if (tid < RR) {
    float s = 0.f;
    for (int dd = 0; dd < DD; ++dd) s += nb[dd][tid];
    norms[tid] = fmaxf(sqrtf(s), 1e-12f);
  }
  __syncthreads();
  if (tid < DD) {
#pragma unroll
    for (int r = 0; r < RR; ++r) v[r] = v[r] / norms[r];
    store_row8(bases0 + ((size_t)b * DD + tid) * RR, v);
#pragma unroll
    for (int r = 0; r < RR; ++r) nb[tid][r] = v[r];
  }
  __syncthreads();
  if (tid < 64) {
    const int r = tid >> 3, s2 = tid & 7;
    float acc = 0.f;
    for (int dd = 0; dd < DD; ++dd) acc += nb[dd][r] * nb[dd][s2];
    btb0[b * 64 + tid] = acc;
  }
  for (int s = 0; s < NSTEPS; ++s) {
    for (int i = tid; i < DD * RR; i += TPB)
      n2acc[(size_t)s * SLOTB + b * DD * RR + i] = 0.f;
    if (tid < 64) ctcacc[(size_t)s * SLOTC + b * 64 + tid] = 0.f;
  }
}

// ---------------------------------------------------------------------------
// make_bases: build this step's bases (bl) + BtB (btbl) in LDS.
// FIRST: load slot0 + btb0. Otherwise compute the multiplicative bases
// update from (bprev, n2prev, ctcprev); block x==0 persists it to bnext.
// ---------------------------------------------------------------------------
template <bool FIRST>
__device__ __forceinline__ void make_bases(
    int b, int tid,
    const float* __restrict__ bprev, const float* __restrict__ btb0,
    const float* __restrict__ n2prev, const float* __restrict__ ctcprev,
    float* __restrict__ bnext, float (&bl)[DD][RR], float* btbl) {
  if (FIRST) {
    reinterpret_cast<float4*>(&bl[0][0])[tid] =
        reinterpret_cast<const float4*>(bprev + (size_t)b * DD * RR)[tid];
    if (tid < 64) btbl[tid] = btb0[b * 64 + tid];
    __syncthreads();
  } else {
    __shared__ float ctcs[64];
    if (tid < 64) ctcs[tid] = ctcprev[b * 64 + tid];
    float row[RR], n2r[RR];
    if (tid < DD) {
      load_row8(bprev + ((size_t)b * DD + tid) * RR, row);
      load_row8(n2prev + ((size_t)b * DD + tid) * RR, n2r);
    }
    __syncthreads();
    float nw[RR];
    if (tid < DD) {
#pragma unroll
      for (int r = 0; r < RR; ++r) {
        float den = EPSV;
#pragma unroll
        for (int s2 = 0; s2 < RR; ++s2) den = fmaf(row[s2], ctcs[s2 * 8 + r], den);
        nw[r] = row[r] * n2r[r] / den;
      }
#pragma unroll
      for (int r = 0; r < RR; ++r) bl[tid][r] = nw[r];
      if (bnext != nullptr && blockIdx.x == 0)
        store_row8(bnext + ((size_t)b * DD + tid) * RR, nw);
    }
    __syncthreads();
    if (tid < 64) {
      const int r = tid >> 3, s2 = tid & 7;
      float acc = 0.f;
      for (int dd = 0; dd < DD; ++dd) acc += bl[dd][r] * bl[dd][s2];
      btbl[tid] = acc;
    }
    __syncthreads();
  }
}

// ---------------------------------------------------------------------------
// k_step<FIRST>: per 512-column tile, two passes over x with 16-deep staged
// loads. sched_barrier(0) pins the batch: all 16 loads issue (and stay live
// in VGPRs) before any consume. __launch_bounds__(TPB,2) raises the VGPR
// budget so the register allocator doesn't re-roll the buffer (round-7 bug:
// VGPR=60 proved the staging was sunk, 1 load in flight, full latency serial).
// grid = (NBLK, BS), TPB threads.
// ---------------------------------------------------------------------------
template <bool FIRST>
__global__ __launch_bounds__(TPB, 2) void k_step(
    const float* __restrict__ xf, float* __restrict__ coef,
    const float* __restrict__ bprev, const float* __restrict__ btb0,
    const float* __restrict__ n2prev, const float* __restrict__ ctcprev,
    float* __restrict__ bnext,
    float* __restrict__ n2cur, float* __restrict__ ctccur) {
  const int b = blockIdx.y;
  const int tid = threadIdx.x;
  const int lane = tid & 63;
  const int wv = tid >> 6;
  const size_t n0 = (size_t)blockIdx.x * NTILE + (size_t)tid * NPT;
  const float* __restrict__ xb = xf + (size_t)b * DD * NN + n0;

  __shared__ float bl[DD][RR];          // 4 KB
  __shared__ float btbl[64];            // 256 B
  __shared__ float nlds[NWAVE][DD][RR]; // 16 KB
  __shared__ float ctcl[NWAVE][64];     // 1 KB

  make_bases<FIRST>(b, tid, bprev, btb0, n2prev, ctcprev, bnext, bl, btbl);

  // ---- pass 1: s = x^T bl, 16 staged loads per group (batch pinned)
  float s0_[RR] = {0.f, 0.f, 0.f, 0.f, 0.f, 0.f, 0.f, 0.f};
  float s1_[RR] = {0.f, 0.f, 0.f, 0.f, 0.f, 0.f, 0.f, 0.f};
#pragma unroll 1
  for (int g = 0; g < DD / GSTEP; ++g) {
    float2 buf[GSTEP];
#pragma unroll
    for (int k = 0; k < GSTEP; ++k)
      buf[k] = *reinterpret_cast<const float2*>(xb + (size_t)(g * GSTEP + k) * NN);
    __builtin_amdgcn_sched_barrier(0);  // all 16 loads issued before consume
#pragma unroll
    for (int k = 0; k < GSTEP; ++k) {
      const int d = g * GSTEP + k;
      const float4 b03 = *reinterpret_cast<const float4*>(&bl[d][0]);
      const float4 b47 = *reinterpret_cast<const float4*>(&bl[d][4]);
      s0_[0] = fmaf(buf[k].x, b03.x, s0_[0]);
      s0_[1] = fmaf(buf[k].x, b03.y, s0_[1]);
      s0_[2] = fmaf(buf[k].x, b03.z, s0_[2]);
      s0_[3] = fmaf(buf[k].x, b03.w, s0_[3]);
      s0_[4] = fmaf(buf[k].x, b47.x, s0_[4]);
      s0_[5] = fmaf(buf[k].x, b47.y, s0_[5]);
      s0_[6] = fmaf(buf[k].x, b47.z, s0_[6]);
      s0_[7] = fmaf(buf[k].x, b47.w, s0_[7]);
      s1_[0] = fmaf(buf[k].y, b03.x, s1_[0]);
      s1_[1] = fmaf(buf[k].y, b03.y, s1_[1]);
      s1_[2] = fmaf(buf[k].y, b03.z, s1_[2]);
      s1_[3] = fmaf(buf[k].y, b03.w, s1_[3]);
      s1_[4] = fmaf(buf[k].y, b47.x, s1_[4]);
      s1_[5] = fmaf(buf[k].y, b47.y, s1_[5]);
      s1_[6] = fmaf(buf[k].y, b47.z, s1_[6]);
      s1_[7] = fmaf(buf[k].y, b47.w, s1_[7]);
    }
  }

  // ---- coef update (both columns)
  float* cp = coef + ((size_t)b * NN + n0) * RR;
  float c0[RR], c1[RR];
  if (FIRST) {
    float m0 = s0_[0], m1 = s1_[0];
#pragma unroll
    for (int r = 1; r < RR; ++r) { m0 = fmaxf(m0, s0_[r]); m1 = fmaxf(m1, s1_[r]); }
    float sum0 = 0.f, sum1 = 0.f;
#pragma unroll
    for (int r = 0; r < RR; ++r) {
      float e0 = __expf(s0_[r] - m0), e1 = __expf(s1_[r] - m1);
      c0[r] = e0; c1[r] = e1; sum0 += e0; sum1 += e1;
    }
#pragma unroll
    for (int r = 0; r < RR; ++r) { c0[r] /= sum0; c1[r] /= sum1; }
  } else {
    load_row8(cp, c0);
    load_row8(cp + RR, c1);
  }
  {
    float cn0[RR], cn1[RR];
#pragma unroll
    for (int r = 0; r < RR; ++r) {
      float d0 = EPSV, d1 = EPSV;
#pragma unroll
      for (int t2 = 0; t2 < RR; ++t2) {
        const float bb = btbl[t2 * 8 + r];
        d0 = fmaf(c0[t2], bb, d0);
        d1 = fmaf(c1[t2], bb, d1);
      }
      cn0[r] = c0[r] * s0_[r] / d0;
      cn1[r] = c1[r] * s1_[r] / d1;
    }
#pragma unroll
    for (int r = 0; r < RR; ++r) { c0[r] = cn0[r]; c1[r] = cn1[r]; }
  }
  store_row8(cp, c0);
  store_row8(cp + RR, c1);

  // ---- pass 2: n2[d][r] += x[d][n]*c[n][r], staged re-read (batch pinned)
#pragma unroll 1
  for (int g = 0; g < DD / GSTEP; ++g) {
    float2 buf[GSTEP];
#pragma unroll
    for (int k = 0; k < GSTEP; ++k)
      buf[k] = *reinterpret_cast<const float2*>(xb + (size_t)(g * GSTEP + k) * NN);
    __builtin_amdgcn_sched_barrier(0);
#pragma unroll
    for (int k = 0; k < GSTEP; ++k) {
      const int d = g * GSTEP + k;
      float p[RR];
#pragma unroll
      for (int r = 0; r < RR; ++r) p[r] = fmaf(buf[k].x, c0[r], buf[k].y * c1[r]);
      float v = tred8(p, lane);
      if (lane < RR) nlds[wv][d][lane] = v;
    }
  }
  // ---- CtC
#pragma unroll
  for (int r = 0; r < RR; ++r) {
    float p2[RR];
#pragma unroll
    for (int s2 = 0; s2 < RR; ++s2) p2[s2] = c0[r] * c0[s2] + c1[r] * c1[s2];
    float v = tred8(p2, lane);
    if (lane < RR) ctcl[wv][r * 8 + lane] = v;
  }
  __syncthreads();

  const float* nf = &nlds[0][0][0];
  for (int i = tid; i < DD * RR; i += TPB) {
    float acc = nf[i] + nf[DD * RR + i] + nf[2 * DD * RR + i] + nf[3 * DD * RR + i];
    atomicAdd(&n2cur[b * DD * RR + i], acc);
  }
  if (tid < 64) {
    float acc = ctcl[0][tid] + ctcl[1][tid] + ctcl[2][tid] + ctcl[3][tid];
    atomicAdd(&ctccur[b * 64 + tid], acc);
  }
}

// ---------------------------------------------------------------------------
// k_final: bases_6 prologue + last coef update (compute_coef) fused with
// reconstruction out = bl @ coef^T. grid = (NBLK, BS), TPB threads.
// ---------------------------------------------------------------------------
__global__ __launch_bounds__(TPB, 2) void k_final(
    const float* __restrict__ xf, const float* __restrict__ coef,
    const float* __restrict__ bprev, const float* __restrict__ n2prev,
    const float* __restrict__ ctcprev, float* __restrict__ out) {
  const int b = blockIdx.y;
  const int tid = threadIdx.x;
  const size_t n0 = (size_t)blockIdx.x * NTILE + (size_t)tid * NPT;
  const float* __restrict__ xb = xf + (size_t)b * DD * NN + n0;

  __shared__ float bl[DD][RR];
  __shared__ float btbl[64];

  make_bases<false>(b, tid, bprev, nullptr, n2prev, ctcprev, nullptr, bl, btbl);

  float s0_[RR] = {0.f, 0.f, 0.f, 0.f, 0.f, 0.f, 0.f, 0.f};
  float s1_[RR] = {0.f, 0.f, 0.f, 0.f, 0.f, 0.f, 0.f, 0.f};
#pragma unroll 1
  for (int g = 0; g < DD / GSTEP; ++g) {
    float2 buf[GSTEP];
#pragma unroll
    for (int k = 0; k < GSTEP; ++k)
      buf[k] = *reinterpret_cast<const float2*>(xb + (size_t)(g * GSTEP + k) * NN);
    __builtin_amdgcn_sched_barrier(0);
#pragma unroll
    for (int k = 0; k < GSTEP; ++k) {
      const int d = g * GSTEP + k;
      const float4 b03 = *reinterpret_cast<const float4*>(&bl[d][0]);
      const float4 b47 = *reinterpret_cast<const float4*>(&bl[d][4]);
      s0_[0] = fmaf(buf[k].x, b03.x, s0_[0]);
      s0_[1] = fmaf(buf[k].x, b03.y, s0_[1]);
      s0_[2] = fmaf(buf[k].x, b03.z, s0_[2]);
      s0_[3] = fmaf(buf[k].x, b03.w, s0_[3]);
      s0_[4] = fmaf(buf[k].x, b47.x, s0_[4]);
      s0_[5] = fmaf(buf[k].x, b47.y, s0_[5]);
      s0_[6] = fmaf(buf[k].x, b47.z, s0_[6]);
      s0_[7] = fmaf(buf[k].x, b47.w, s0_[7]);
      s1_[0] = fmaf(buf[k].y, b03.x, s1_[0]);
      s1_[1] = fmaf(buf[k].y, b03.y, s1_[1]);
      s1_[2] = fmaf(buf[k].y, b03.z, s1_[2]);
      s1_[3] = fmaf(buf[k].y, b03.w, s1_[3]);
      s1_[4] = fmaf(buf[k].y, b47.x, s1_[4]);
      s1_[5] = fmaf(buf[k].y, b47.y, s1_[5]);
      s1_[6] = fmaf(buf[k].y, b47.z, s1_[6]);
      s1_[7] = fmaf(buf[k].y, b47.w, s1_[7]);
    }
  }

  float c0[RR], c1[RR];
  const float* cp = coef + ((size_t)b * NN + n0) * RR;
  load_row8(cp, c0);
  load_row8(cp + RR, c1);
  {
    float cn0[RR], cn1[RR];
#pragma unroll
    for (int r = 0; r < RR; ++r) {
      float d0 = EPSV, d1 = EPSV;
#pragma unroll
      for (int t2 = 0; t2 < RR; ++t2) {
        const float bb = btbl[t2 * 8 + r];
        d0 = fmaf(c0[t2], bb, d0);
        d1 = fmaf(c1[t2], bb, d1);
      }
      cn0[r] = c0[r] * s0_[r] / d0;
      cn1[r] = c1[r] * s1_[r] / d1;
    }
#pragma unroll
    for (int r = 0; r < RR; ++r) { c0[r] = cn0[r]; c1[r] = cn1[r]; }
  }

  float* ob = out + (size_t)b * DD * NN + n0;
#pragma unroll 4
  for (int d = 0; d < DD; ++d) {
    const float4 b03 = *reinterpret_cast<const float4*>(&bl[d][0]);
    const float4 b47 = *reinterpret_cast<const float4*>(&bl[d][4]);
    float ox = b03.x * c0[0], oy = b03.x * c1[0];
    ox = fmaf(b03.y, c0[1], ox); oy = fmaf(b03.y, c1[1], oy);
    ox = fmaf(b03.z, c0[2], ox); oy = fmaf(b03.z, c1[2], oy);
    ox = fmaf(b03.w, c0[3], ox); oy = fmaf(b03.w, c1[3], oy);
    ox = fmaf(b47.x, c0[4], ox); oy = fmaf(b47.x, c1[4], oy);
    ox = fmaf(b47.y, c0[5], ox); oy = fmaf(b47.y, c1[5], oy);
    ox = fmaf(b47.z, c0[6], ox); oy = fmaf(b47.z, c1[6], oy);
    ox = fmaf(b47.w, c0[7], ox); oy = fmaf(b47.w, c1[7], oy);
    *reinterpret_cast<float2*>(ob + (size_t)d * NN) = make_float2(ox, oy);
  }
}

// ---------------------------------------------------------------------------
extern "C" void kernel_launch(void* const* d_in, const int* in_sizes, int n_in,
                              void* d_out, int out_size, void* d_ws, size_t ws_size,
                              hipStream_t stream) {
  const float* x = (const float*)d_in[0];   // [BS, DD, NN] fp32
  const float* bi = (const float*)d_in[1];  // [BS, DD, RR] fp32
  float* out = (float*)d_out;               // [BS, DD, NN] fp32

  // workspace (floats): coef | bases_store[6] | btb0 | n2acc[6] | ctcacc[6]
  float* coef = (float*)d_ws;                          // BS*NN*RR
  float* bases_store = coef + (size_t)BS * NN * RR;    // 6 * SLOTB
  float* btb0 = bases_store + (size_t)6 * SLOTB;       // BS*64
  float* n2acc = btb0 + (size_t)BS * 64;               // 6 * SLOTB
  float* ctcacc = n2acc + (size_t)6 * SLOTB;           // 6 * SLOTC

  dim3 gbig(NBLK, BS);

  k_init<<<dim3(BS), TPB, 0, stream>>>(bi, bases_store, btb0, n2acc, ctcacc);

  k_step<true><<<gbig, TPB, 0, stream>>>(x, coef, bases_store, btb0, nullptr,
                                         nullptr, nullptr, n2acc, ctcacc);
  for (int s = 1; s < NSTEPS; ++s) {
    k_step<false><<<gbig, TPB, 0, stream>>>(
        x, coef, bases_store + (size_t)(s - 1) * SLOTB, nullptr,
        n2acc + (size_t)(s - 1) * SLOTB, ctcacc + (size_t)(s - 1) * SLOTC,
        bases_store + (size_t)s * SLOTB, n2acc + (size_t)s * SLOTB,
        ctcacc + (size_t)s * SLOTC);
  }

  k_final<<<gbig, TPB, 0, stream>>>(
      x, coef, bases_store + (size_t)5 * SLOTB, n2acc + (size_t)5 * SLOTB,
      ctcacc + (size_t)5 * SLOTC, out);
}